// Round 14
// baseline (651.645 us; speedup 1.0000x reference)
//
#include <hip/hip_runtime.h>
#include <math.h>

#define NN 30000
#define NE 480000
#define TPB 256
#define ETPB 64

// ---- CSR-path workspace layout (float offsets) ----
#define NG_OFF    0           // 600000 g vectors (Wd folded)
#define NW1K_OFF  600000      // 512
#define NW1V_OFF  600512      // 512
#define NW2K_OFF  601024      // 9216
#define NW2V_OFF  610240      // 9216
#define NCNT_OFF  619456      // 30000 int   (cnt, c2 adjacent: one memset)
#define NC2_OFF   649456      // 30000 int
#define NOFF_OFF  679456      // 30008 int
#define NEVS_OFF  709464      // 480000 f32
#define NVSC_OFF  1189464     // 9600000 halfs
#define NTOT      5989464     // floats (~24 MB)

#define INV_SQRT8  0.35355339059327376f
#define SIG_SS     0.02209708691207961f
#define SIG_UU     0.01804219591217582f
#define SIG_SU     0.02209708691207961f
#define SIG_US     0.03125f
#define D0S        0.08838834764831845f
#define D1S        0.10206207261596575f

// single-wave block: HW executes a wave's DS ops in order; this only pins
// compile-time ordering (no s_barrier, no waitcnt drain). r13-verified.
#define WBAR() __builtin_amdgcn_wave_barrier()

typedef _Float16 half2v __attribute__((ext_vector_type(2)));
typedef _Float16 f16x4  __attribute__((ext_vector_type(4)));
typedef _Float16 f16x8  __attribute__((ext_vector_type(8)));
typedef float    f32x4  __attribute__((ext_vector_type(4)));

__device__ __forceinline__ float fdot2(half2v a, half2v b, float c) {
    return __builtin_amdgcn_fdot2(a, b, c, false);
}

// ---------- fused prep: weight pack (0..17) + g vectors (18..135) + edge hist (136..)
__global__ __launch_bounds__(TPB) void prep_all(
    const float* __restrict__ x, const int* __restrict__ ei,
    const float* __restrict__ wq0, const float* __restrict__ wq1,
    const float* __restrict__ wk1, const float* __restrict__ wk2,
    const float* __restrict__ wv1, const float* __restrict__ wv2,
    const float* __restrict__ wd0, const float* __restrict__ wd1,
    half2v* __restrict__ w1pk, half2v* __restrict__ w1pv,
    _Float16* __restrict__ w2fk, _Float16* __restrict__ w2fv,
    float* __restrict__ g, int* __restrict__ cnt)
{
    const int b = blockIdx.x;
    if (b < 18) {
        int tid = b * TPB + threadIdx.x;   // 4608 exactly
        {
            int p = tid / 2304, rem = tid % 2304;
            int fg = rem >> 6, l = rem & 63;
            int t = fg >> 1, s = fg & 1;
            int kbase = s * 32 + (l >> 4) * 8;
            int m = t * 16 + (l & 15);
            float sig = (m < 128) ? SIG_SS : (m < 192) ? SIG_UU
                      : (m < 256) ? SIG_SU : SIG_US;
            const float* W2 = p ? wv2 : wk2;
            _Float16* dst = (p ? w2fv : w2fk) + (size_t)(fg * 64 + l) * 8;
#pragma unroll
            for (int jj = 0; jj < 8; ++jj)
                dst[jj] = (_Float16)(W2[(size_t)(kbase + jj) * 288 + m] * sig);
        }
        if (tid < 512) {
            int hh = tid >> 3, a2 = tid & 7;
            w1pk[tid] = half2v{(_Float16)(wk1[(2 * a2) * 64 + hh] * 0.25f),
                               (_Float16)(wk1[(2 * a2 + 1) * 64 + hh] * 0.25f)};
            w1pv[tid] = half2v{(_Float16)(wv1[(2 * a2) * 64 + hh] * 0.25f),
                               (_Float16)(wv1[(2 * a2 + 1) * 64 + hh] * 0.25f)};
        }
    } else if (b < 136) {
        // ---- per-node g = Wd-folded q (r12-verified) ----
        int n = (b - 18) * TPB + threadIdx.x;
        if (n >= NN) return;
        const float* xr = x + (size_t)n * 40;
        float* o = g + (size_t)n * 20;
        float q0[8];
#pragma unroll
        for (int bb = 0; bb < 8; ++bb) {
            float acc = 0.f;
#pragma unroll
            for (int a = 0; a < 16; ++a) acc += xr[a] * wq0[a * 8 + bb];
            q0[bb] = acc * 0.25f;
        }
#pragma unroll
        for (int bb = 0; bb < 8; ++bb) {
            float acc = 0.f;
#pragma unroll
            for (int a = 0; a < 8; ++a) acc += q0[a] * wd0[a * 8 + bb];
            o[bb] = acc * D0S;
        }
        float q1[4][3];
#pragma unroll
        for (int bb = 0; bb < 4; ++bb)
#pragma unroll
            for (int c = 0; c < 3; ++c) {
                float acc = 0.f;
#pragma unroll
                for (int a = 0; a < 8; ++a) acc += xr[16 + a * 3 + c] * wq1[a * 4 + bb];
                q1[bb][c] = acc * INV_SQRT8;
            }
#pragma unroll
        for (int bb = 0; bb < 4; ++bb)
#pragma unroll
            for (int c = 0; c < 3; ++c) {
                float acc = 0.f;
#pragma unroll
                for (int a = 0; a < 4; ++a) acc += q1[a][c] * wd1[a * 4 + bb];
                o[8 + bb * 3 + c] = acc * D1S;
            }
    } else {
        // ---- edge histogram (cnt pre-zeroed by memset) ----
        int e = (b - 136) * TPB + threadIdx.x;   // 1875 blocks, exact
        atomicAdd(cnt + ei[NE + e], 1);
    }
}

__global__ __launch_bounds__(1024) void scan_k(const int* __restrict__ cnt,
                                               int* __restrict__ offs)
{
    __shared__ int part[1024];
    const int t = threadIdx.x;
    int local[30];
    int s = 0;
#pragma unroll
    for (int k = 0; k < 30; ++k) {
        int idx = t * 30 + k;
        local[k] = s;
        s += (idx < NN) ? cnt[idx] : 0;
    }
    part[t] = s;
    __syncthreads();
    for (int off = 1; off < 1024; off <<= 1) {
        int v = (t >= off) ? part[t - off] : 0;
        __syncthreads();
        part[t] += v;
        __syncthreads();
    }
    int tbase = (t == 0) ? 0 : part[t - 1];
#pragma unroll
    for (int k = 0; k < 30; ++k) {
        int idx = t * 30 + k;
        if (idx < NN) offs[idx] = tbase + local[k];
    }
    if (t == 1023) offs[NN] = part[1023];
}

// ---------- fused k+v edge kernel: r13 algebra; split sh_h (292-stride sh_R);
// ---------- h_k/h_v computed together from one em2 (single emb read)
__global__ __launch_bounds__(ETPB, 4) void edge_fused(
    const float* __restrict__ x, const int* __restrict__ ei,
    const float* __restrict__ eattr, const float* __restrict__ emb,
    const float* __restrict__ el,
    const half2v* __restrict__ w1pk, const f16x8* __restrict__ w2fk,
    const half2v* __restrict__ w1pv, const f16x8* __restrict__ w2fv,
    const float* __restrict__ gn, const int* __restrict__ offs,
    int* __restrict__ c2,
    float* __restrict__ evs, _Float16* __restrict__ vsc)
{
    __shared__ __align__(16) _Float16 sh_h[16][72];   // 144B rows: b128-aligned
    __shared__ __align__(16) _Float16 sh_R[16][292];  // 146-dw stride: 2-way (free)
    __shared__ float sh_d[16][4];
    __shared__ int sh_pe[16];

    const int l = threadIdx.x;            // single wave
    const int q = l >> 4, n = l & 15;
    const int e = blockIdx.x * 16 + n;
    const int i = ei[e];
    const int j = ei[NE + e];
    const float4 ea = *(const float4*)(eattr + (size_t)e * 4);
    const float y0 = ea.x, y1x = ea.y, y1y = ea.z, y1z = ea.w;
    const int b0 = (q < 2) ? (4 * q) : (2 * (q - 2));

    // in-kernel rank (r13-verified): CSR slot, broadcast via LDS
    if (q == 0) sh_pe[n] = offs[j] + atomicAdd(c2 + j, 1);

    // ---- both hidden layers from ONE em2 (one emb read + one conversion) ----
    f16x4 hv_reg[4];
    {
        half2v em2[8];
        const float4* ep = (const float4*)(emb + (size_t)e * 16);
#pragma unroll
        for (int p = 0; p < 4; ++p) {
            float4 v = ep[p];
            em2[2 * p]     = half2v{(_Float16)v.x, (_Float16)v.y};
            em2[2 * p + 1] = half2v{(_Float16)v.z, (_Float16)v.w};
        }
#pragma unroll
        for (int k4 = 0; k4 < 4; ++k4) {
            f16x4 hk, hv;
#pragma unroll
            for (int ii = 0; ii < 4; ++ii) {
                const int k = q * 16 + 4 * k4 + ii;
                const half2v* wrk = w1pk + (size_t)k * 8;
                const half2v* wrv = w1pv + (size_t)k * 8;
                float a0 = 0.f, a1 = 0.f, c0 = 0.f, c1 = 0.f;
#pragma unroll
                for (int a2 = 0; a2 < 4; ++a2) {
                    a0 = fdot2(em2[2 * a2],     wrk[2 * a2],     a0);
                    a1 = fdot2(em2[2 * a2 + 1], wrk[2 * a2 + 1], a1);
                    c0 = fdot2(em2[2 * a2],     wrv[2 * a2],     c0);
                    c1 = fdot2(em2[2 * a2 + 1], wrv[2 * a2 + 1], c1);
                }
                const float zk = a0 + a1, zv = c0 + c1;
                hk[ii] = (_Float16)(zk * __builtin_amdgcn_rcpf(1.f + __expf(-zk)));
                hv[ii] = (_Float16)(zv * __builtin_amdgcn_rcpf(1.f + __expf(-zv)));
            }
            *(f16x4*)&sh_h[n][q * 16 + 4 * k4] = hk;
            hv_reg[k4] = hv;
        }
    }
    WBAR();
    const int pe = sh_pe[n];

    // ================= K GEMM =================
    {
        f16x8 B0 = *(const f16x8*)&sh_h[n][q * 8];
        f16x8 B1 = *(const f16x8*)&sh_h[n][32 + q * 8];
        f32x4 acc[18];
#pragma unroll
        for (int t = 0; t < 18; ++t) acc[t] = f32x4{0.f, 0.f, 0.f, 0.f};
#pragma unroll
        for (int t = 0; t < 18; ++t) {
            f16x8 A0 = w2fk[(t * 2 + 0) * 64 + l];
            f16x8 A1 = w2fk[(t * 2 + 1) * 64 + l];
            acc[t] = __builtin_amdgcn_mfma_f32_16x16x32_f16(A0, B0, acc[t], 0, 0, 0);
            acc[t] = __builtin_amdgcn_mfma_f32_16x16x32_f16(A1, B1, acc[t], 0, 0, 0);
        }
#pragma unroll
        for (int t = 0; t < 18; ++t) {
            f16x4 rv = {(_Float16)acc[t][0], (_Float16)acc[t][1],
                        (_Float16)acc[t][2], (_Float16)acc[t][3]};
            *(f16x4*)&sh_R[n][t * 16 + 4 * q] = rv;
        }
    }
    WBAR();
    // ---- k epilogue: score partials (b-sliced; Wd pre-folded into g) ----
    {
        float xr[40];
        const float4* xp = (const float4*)(x + (size_t)i * 40);
#pragma unroll
        for (int p = 0; p < 10; ++p) {
            float4 v = xp[p];
            xr[4 * p] = v.x; xr[4 * p + 1] = v.y;
            xr[4 * p + 2] = v.z; xr[4 * p + 3] = v.w;
        }
        const float* gj = gn + (size_t)j * 20;
        float pd = 0.f;
        if (q < 2) {
            float ssv[4] = {0.f, 0.f, 0.f, 0.f};
            float uuv[4] = {0.f, 0.f, 0.f, 0.f};
#pragma unroll
            for (int a = 0; a < 16; ++a) {
                const f16x4 rv = *(const f16x4*)&sh_R[n][a * 8 + b0];
#pragma unroll
                for (int r = 0; r < 4; ++r) ssv[r] += xr[a] * (float)rv[r];
            }
#pragma unroll
            for (int a = 0; a < 8; ++a) {
                const float xy = xr[16 + a * 3] * y1x + xr[17 + a * 3] * y1y
                               + xr[18 + a * 3] * y1z;
                const f16x4 rv = *(const f16x4*)&sh_R[n][128 + a * 8 + b0];
#pragma unroll
                for (int r = 0; r < 4; ++r) uuv[r] += xy * (float)rv[r];
            }
#pragma unroll
            for (int r = 0; r < 4; ++r)
                pd += (y0 * ssv[r] + uuv[r]) * gj[b0 + r];
        } else {
            float suv[2] = {0.f, 0.f};
            float usv[2][3] = {{0.f, 0.f, 0.f}, {0.f, 0.f, 0.f}};
#pragma unroll
            for (int a = 0; a < 16; ++a) {
                const half2v rv = *(const half2v*)&sh_R[n][192 + a * 4 + b0];
                suv[0] += xr[a] * (float)rv[0];
                suv[1] += xr[a] * (float)rv[1];
            }
#pragma unroll
            for (int a = 0; a < 8; ++a) {
                const half2v rv = *(const half2v*)&sh_R[n][256 + a * 4 + b0];
#pragma unroll
                for (int bb = 0; bb < 2; ++bb) {
                    const float wv = (float)rv[bb];
                    usv[bb][0] += xr[16 + a * 3] * wv;
                    usv[bb][1] += xr[17 + a * 3] * wv;
                    usv[bb][2] += xr[18 + a * 3] * wv;
                }
            }
#pragma unroll
            for (int bb = 0; bb < 2; ++bb) {
                const float k1x = suv[bb] * y1x + y0 * usv[bb][0];
                const float k1y = suv[bb] * y1y + y0 * usv[bb][1];
                const float k1z = suv[bb] * y1z + y0 * usv[bb][2];
                const float* gr = gj + 8 + (b0 + bb) * 3;
                pd += k1x * gr[0] + k1y * gr[1] + k1z * gr[2];
            }
        }
        sh_d[n][q] = pd;
    }
    WBAR();
    if (q == 0) {
        const float d = sh_d[n][0] + sh_d[n][1] + sh_d[n][2] + sh_d[n][3];
        const float len = el[e];
        const float tt = 10.f * (1.f - len / 3.15f);
        float cut = 0.f;
        if (tt > 0.f) cut = __expf(-1.f / fmaxf(tt, 1e-6f));
        evs[pe] = cut * __expf(d);
    }
    WBAR();   // all k-epilogue sh_R reads precede v dump (in-order DS, pinned order)

    // ================= V PASS: stage h_v from registers =================
#pragma unroll
    for (int k4 = 0; k4 < 4; ++k4)
        *(f16x4*)&sh_h[n][q * 16 + 4 * k4] = hv_reg[k4];
    WBAR();
    {
        f16x8 B0 = *(const f16x8*)&sh_h[n][q * 8];
        f16x8 B1 = *(const f16x8*)&sh_h[n][32 + q * 8];
        f32x4 acc[18];
#pragma unroll
        for (int t = 0; t < 18; ++t) acc[t] = f32x4{0.f, 0.f, 0.f, 0.f};
#pragma unroll
        for (int t = 0; t < 18; ++t) {
            f16x8 A0 = w2fv[(t * 2 + 0) * 64 + l];
            f16x8 A1 = w2fv[(t * 2 + 1) * 64 + l];
            acc[t] = __builtin_amdgcn_mfma_f32_16x16x32_f16(A0, B0, acc[t], 0, 0, 0);
            acc[t] = __builtin_amdgcn_mfma_f32_16x16x32_f16(A1, B1, acc[t], 0, 0, 0);
        }
#pragma unroll
        for (int t = 0; t < 18; ++t) {
            f16x4 rv = {(_Float16)acc[t][0], (_Float16)acc[t][1],
                        (_Float16)acc[t][2], (_Float16)acc[t][3]};
            *(f16x4*)&sh_R[n][t * 16 + 4 * q] = rv;
        }
    }
    WBAR();
    // ---- v epilogue: store 20-half record at CSR slot ----
    {
        float xr[40];
        const float4* xp = (const float4*)(x + (size_t)i * 40);
#pragma unroll
        for (int p = 0; p < 10; ++p) {
            float4 v = xp[p];
            xr[4 * p] = v.x; xr[4 * p + 1] = v.y;
            xr[4 * p + 2] = v.z; xr[4 * p + 3] = v.w;
        }
        _Float16* rec = vsc + (size_t)pe * 20;
        if (q < 2) {
            float ssv[4] = {0.f, 0.f, 0.f, 0.f};
            float uuv[4] = {0.f, 0.f, 0.f, 0.f};
#pragma unroll
            for (int a = 0; a < 16; ++a) {
                const f16x4 rv = *(const f16x4*)&sh_R[n][a * 8 + b0];
#pragma unroll
                for (int r = 0; r < 4; ++r) ssv[r] += xr[a] * (float)rv[r];
            }
#pragma unroll
            for (int a = 0; a < 8; ++a) {
                const float xy = xr[16 + a * 3] * y1x + xr[17 + a * 3] * y1y
                               + xr[18 + a * 3] * y1z;
                const f16x4 rv = *(const f16x4*)&sh_R[n][128 + a * 8 + b0];
#pragma unroll
                for (int r = 0; r < 4; ++r) uuv[r] += xy * (float)rv[r];
            }
            f16x4 o;
#pragma unroll
            for (int r = 0; r < 4; ++r) o[r] = (_Float16)(y0 * ssv[r] + uuv[r]);
            *(f16x4*)&rec[b0] = o;
        } else {
            float suv[2] = {0.f, 0.f};
            float usv[2][3] = {{0.f, 0.f, 0.f}, {0.f, 0.f, 0.f}};
#pragma unroll
            for (int a = 0; a < 16; ++a) {
                const half2v rv = *(const half2v*)&sh_R[n][192 + a * 4 + b0];
                suv[0] += xr[a] * (float)rv[0];
                suv[1] += xr[a] * (float)rv[1];
            }
#pragma unroll
            for (int a = 0; a < 8; ++a) {
                const half2v rv = *(const half2v*)&sh_R[n][256 + a * 4 + b0];
#pragma unroll
                for (int bb = 0; bb < 2; ++bb) {
                    const float wv = (float)rv[bb];
                    usv[bb][0] += xr[16 + a * 3] * wv;
                    usv[bb][1] += xr[17 + a * 3] * wv;
                    usv[bb][2] += xr[18 + a * 3] * wv;
                }
            }
            float k1v[2][3];
#pragma unroll
            for (int bb = 0; bb < 2; ++bb) {
                k1v[bb][0] = suv[bb] * y1x + y0 * usv[bb][0];
                k1v[bb][1] = suv[bb] * y1y + y0 * usv[bb][1];
                k1v[bb][2] = suv[bb] * y1z + y0 * usv[bb][2];
            }
            const int base = 8 + b0 * 3;
            *(half2v*)&rec[base]     = half2v{(_Float16)k1v[0][0], (_Float16)k1v[0][1]};
            *(half2v*)&rec[base + 2] = half2v{(_Float16)k1v[0][2], (_Float16)k1v[1][0]};
            *(half2v*)&rec[base + 4] = half2v{(_Float16)k1v[1][1], (_Float16)k1v[1][2]};
        }
    }
}

// ---------- node gather: one wave per node, all lanes active, zero atomics ----------
__global__ __launch_bounds__(TPB) void node_gather(
    const int* __restrict__ offs,
    const float* __restrict__ evs, const _Float16* __restrict__ vsc,
    float* __restrict__ out)
{
    const int wv = threadIdx.x >> 6, lane = threadIdx.x & 63;
    const int j = blockIdx.x * 4 + wv;
    if (j >= NN) return;
    const int o0 = offs[j], cnt = offs[j + 1] - o0;

    float s = 0.f;
    for (int t = lane; t < cnt; t += 64) s += evs[o0 + t];
#pragma unroll
    for (int d = 1; d < 64; d <<= 1) s += __shfl_xor(s, d);
    const float invZ = (s > 0.f) ? (1.f / s) : 0.f;

    const int g = lane / 20, c = lane % 20;
    float acc = 0.f;
    if (g < 3) {
        for (int t = g; t < cnt; t += 3) {
            const float ev = evs[o0 + t];
            const float wgt = sqrtf(fmaxf(ev * invZ, 0.f));
            acc += wgt * (float)vsc[(size_t)(o0 + t) * 20 + c];
        }
    }
    const float a1 = __shfl(acc, lane + 20);
    const float a2 = __shfl(acc, lane + 40);
    if (lane < 20) out[(size_t)j * 20 + lane] = acc + a1 + a2;
}

extern "C" void kernel_launch(void* const* d_in, const int* in_sizes, int n_in,
                              void* d_out, int out_size, void* d_ws, size_t ws_size,
                              hipStream_t stream)
{
    const float* x     = (const float*)d_in[0];
    const int*   eidx  = (const int*)d_in[1];
    const float* eattr = (const float*)d_in[2];
    const float* emb   = (const float*)d_in[3];
    const float* elen  = (const float*)d_in[4];
    const float* wq0   = (const float*)d_in[5];
    const float* wq1   = (const float*)d_in[6];
    const float* wk1   = (const float*)d_in[7];
    const float* wk2   = (const float*)d_in[8];
    const float* wv1   = (const float*)d_in[9];
    const float* wv2   = (const float*)d_in[10];
    const float* wd0   = (const float*)d_in[11];
    const float* wd1   = (const float*)d_in[12];

    float* ws  = (float*)d_ws;
    float* out = (float*)d_out;

    half2v* w1pk = (half2v*)(ws + NW1K_OFF);
    half2v* w1pv = (half2v*)(ws + NW1V_OFF);
    _Float16* w2fk = (_Float16*)(ws + NW2K_OFF);
    _Float16* w2fv = (_Float16*)(ws + NW2V_OFF);
    int* cnt  = (int*)(ws + NCNT_OFF);
    int* c2   = (int*)(ws + NC2_OFF);
    int* offs = (int*)(ws + NOFF_OFF);
    float* evs = ws + NEVS_OFF;
    _Float16* vsc = (_Float16*)(ws + NVSC_OFF);

    // zero cnt + c2 (adjacent) in one memset
    hipMemsetAsync(cnt, 0, 2 * NN * sizeof(int), stream);

    // prep: weights + g + histogram (1875 hist blocks)
    prep_all<<<136 + NE / TPB, TPB, 0, stream>>>(
        x, eidx, wq0, wq1, wk1, wk2, wv1, wv2, wd0, wd1,
        w1pk, w1pv, w2fk, w2fv, ws + NG_OFF, cnt);

    scan_k<<<1, 1024, 0, stream>>>(cnt, offs);

    edge_fused<<<NE / 16, ETPB, 0, stream>>>(
        x, eidx, eattr, emb, elen,
        w1pk, (const f16x8*)w2fk, w1pv, (const f16x8*)w2fv,
        ws + NG_OFF, offs, c2, evs, vsc);

    node_gather<<<(NN + 3) / 4, TPB, 0, stream>>>(offs, evs, vsc, out);
}

// Round 15
// 355.253 us; speedup vs baseline: 1.8343x; 1.8343x over previous
//
#include <hip/hip_runtime.h>
#include <math.h>

#define NN 30000
#define NE 480000
#define TPB 256
#define ETPB 64

// ---- CSR-path workspace layout (float offsets) ----
#define NG_OFF    0           // 600000 g vectors (Wd folded)
#define NW1K_OFF  600000      // 512
#define NW1V_OFF  600512      // 512
#define NW2K_OFF  601024      // 9216
#define NW2V_OFF  610240      // 9216
#define NCNT_OFF  619456      // 30000 int   (cnt, c2 adjacent: one memset)
#define NC2_OFF   649456      // 30000 int
#define NOFF_OFF  679456      // 30008 int
#define NEVS_OFF  709464      // 480000 f32
#define NVSC_OFF  1189464     // 9600000 halfs
#define NTOT      5989464     // floats (~24 MB)

#define INV_SQRT8  0.35355339059327376f
#define SIG_SS     0.02209708691207961f
#define SIG_UU     0.01804219591217582f
#define SIG_SU     0.02209708691207961f
#define SIG_US     0.03125f
#define D0S        0.08838834764831845f
#define D1S        0.10206207261596575f

// single-wave block: HW executes a wave's DS ops in order; this only pins
// compile-time ordering (no s_barrier, no waitcnt drain). r13-verified.
#define WBAR() __builtin_amdgcn_wave_barrier()

typedef _Float16 half2v __attribute__((ext_vector_type(2)));
typedef _Float16 f16x4  __attribute__((ext_vector_type(4)));
typedef _Float16 f16x8  __attribute__((ext_vector_type(8)));
typedef float    f32x4  __attribute__((ext_vector_type(4)));

__device__ __forceinline__ float fdot2(half2v a, half2v b, float c) {
    return __builtin_amdgcn_fdot2(a, b, c, false);
}

// ---------- fused prep: weight pack (0..17) + g vectors (18..135) + edge hist (136..)
__global__ __launch_bounds__(TPB) void prep_all(
    const float* __restrict__ x, const int* __restrict__ ei,
    const float* __restrict__ wq0, const float* __restrict__ wq1,
    const float* __restrict__ wk1, const float* __restrict__ wk2,
    const float* __restrict__ wv1, const float* __restrict__ wv2,
    const float* __restrict__ wd0, const float* __restrict__ wd1,
    half2v* __restrict__ w1pk, half2v* __restrict__ w1pv,
    _Float16* __restrict__ w2fk, _Float16* __restrict__ w2fv,
    float* __restrict__ g, int* __restrict__ cnt)
{
    const int b = blockIdx.x;
    if (b < 18) {
        int tid = b * TPB + threadIdx.x;   // 4608 exactly
        {
            int p = tid / 2304, rem = tid % 2304;
            int fg = rem >> 6, l = rem & 63;
            int t = fg >> 1, s = fg & 1;
            int kbase = s * 32 + (l >> 4) * 8;
            int m = t * 16 + (l & 15);
            float sig = (m < 128) ? SIG_SS : (m < 192) ? SIG_UU
                      : (m < 256) ? SIG_SU : SIG_US;
            const float* W2 = p ? wv2 : wk2;
            _Float16* dst = (p ? w2fv : w2fk) + (size_t)(fg * 64 + l) * 8;
#pragma unroll
            for (int jj = 0; jj < 8; ++jj)
                dst[jj] = (_Float16)(W2[(size_t)(kbase + jj) * 288 + m] * sig);
        }
        if (tid < 512) {
            int hh = tid >> 3, a2 = tid & 7;
            w1pk[tid] = half2v{(_Float16)(wk1[(2 * a2) * 64 + hh] * 0.25f),
                               (_Float16)(wk1[(2 * a2 + 1) * 64 + hh] * 0.25f)};
            w1pv[tid] = half2v{(_Float16)(wv1[(2 * a2) * 64 + hh] * 0.25f),
                               (_Float16)(wv1[(2 * a2 + 1) * 64 + hh] * 0.25f)};
        }
    } else if (b < 136) {
        // ---- per-node g = Wd-folded q (r12-verified) ----
        int n = (b - 18) * TPB + threadIdx.x;
        if (n >= NN) return;
        const float* xr = x + (size_t)n * 40;
        float* o = g + (size_t)n * 20;
        float q0[8];
#pragma unroll
        for (int bb = 0; bb < 8; ++bb) {
            float acc = 0.f;
#pragma unroll
            for (int a = 0; a < 16; ++a) acc += xr[a] * wq0[a * 8 + bb];
            q0[bb] = acc * 0.25f;
        }
#pragma unroll
        for (int bb = 0; bb < 8; ++bb) {
            float acc = 0.f;
#pragma unroll
            for (int a = 0; a < 8; ++a) acc += q0[a] * wd0[a * 8 + bb];
            o[bb] = acc * D0S;
        }
        float q1[4][3];
#pragma unroll
        for (int bb = 0; bb < 4; ++bb)
#pragma unroll
            for (int c = 0; c < 3; ++c) {
                float acc = 0.f;
#pragma unroll
                for (int a = 0; a < 8; ++a) acc += xr[16 + a * 3 + c] * wq1[a * 4 + bb];
                q1[bb][c] = acc * INV_SQRT8;
            }
#pragma unroll
        for (int bb = 0; bb < 4; ++bb)
#pragma unroll
            for (int c = 0; c < 3; ++c) {
                float acc = 0.f;
#pragma unroll
                for (int a = 0; a < 4; ++a) acc += q1[a][c] * wd1[a * 4 + bb];
                o[8 + bb * 3 + c] = acc * D1S;
            }
    } else {
        // ---- edge histogram (cnt pre-zeroed by memset) ----
        int e = (b - 136) * TPB + threadIdx.x;   // 1875 blocks, exact
        atomicAdd(cnt + ei[NE + e], 1);
    }
}

__global__ __launch_bounds__(1024) void scan_k(const int* __restrict__ cnt,
                                               int* __restrict__ offs)
{
    __shared__ int part[1024];
    const int t = threadIdx.x;
    int local[30];
    int s = 0;
#pragma unroll
    for (int k = 0; k < 30; ++k) {
        int idx = t * 30 + k;
        local[k] = s;
        s += (idx < NN) ? cnt[idx] : 0;
    }
    part[t] = s;
    __syncthreads();
    for (int off = 1; off < 1024; off <<= 1) {
        int v = (t >= off) ? part[t - off] : 0;
        __syncthreads();
        part[t] += v;
        __syncthreads();
    }
    int tbase = (t == 0) ? 0 : part[t - 1];
#pragma unroll
    for (int k = 0; k < 30; ++k) {
        int idx = t * 30 + k;
        if (idx < NN) offs[idx] = tbase + local[k];
    }
    if (t == 1023) offs[NN] = part[1023];
}

// ---------- fused k+v edge kernel: one emb read; h_v in LDS (no register carry);
// ---------- sh_R 292-stride (2-way-free, r14-verified conflict fix)
__global__ __launch_bounds__(ETPB, 4) void edge_fused(
    const float* __restrict__ x, const int* __restrict__ ei,
    const float* __restrict__ eattr, const float* __restrict__ emb,
    const float* __restrict__ el,
    const half2v* __restrict__ w1pk, const f16x8* __restrict__ w2fk,
    const half2v* __restrict__ w1pv, const f16x8* __restrict__ w2fv,
    const float* __restrict__ gn, const int* __restrict__ offs,
    int* __restrict__ c2,
    float* __restrict__ evs, _Float16* __restrict__ vsc)
{
    __shared__ __align__(16) _Float16 sh_R[16][292];  // h_k staged, then R dumps
    __shared__ __align__(16) _Float16 sh_hv[16][72];  // h_v parked for the V GEMM
    __shared__ float sh_d[16][4];
    __shared__ int sh_pe[16];

    const int l = threadIdx.x;            // single wave
    const int q = l >> 4, n = l & 15;
    const int e = blockIdx.x * 16 + n;
    const int i = ei[e];
    const int j = ei[NE + e];
    const float4 ea = *(const float4*)(eattr + (size_t)e * 4);
    const float y0 = ea.x, y1x = ea.y, y1y = ea.z, y1z = ea.w;
    const int b0 = (q < 2) ? (4 * q) : (2 * (q - 2));

    // in-kernel rank (r13-verified): CSR slot, broadcast via LDS
    if (q == 0) sh_pe[n] = offs[j] + atomicAdd(c2 + j, 1);

    // ---- both hidden layers from ONE em2; h_k -> sh_R, h_v -> sh_hv ----
    {
        half2v em2[8];
        const float4* ep = (const float4*)(emb + (size_t)e * 16);
#pragma unroll
        for (int p = 0; p < 4; ++p) {
            float4 v = ep[p];
            em2[2 * p]     = half2v{(_Float16)v.x, (_Float16)v.y};
            em2[2 * p + 1] = half2v{(_Float16)v.z, (_Float16)v.w};
        }
#pragma unroll
        for (int k4 = 0; k4 < 4; ++k4) {
            f16x4 hk, hv;
#pragma unroll
            for (int ii = 0; ii < 4; ++ii) {
                const int k = q * 16 + 4 * k4 + ii;
                const half2v* wrk = w1pk + (size_t)k * 8;
                const half2v* wrv = w1pv + (size_t)k * 8;
                float a0 = 0.f, a1 = 0.f, c0 = 0.f, c1 = 0.f;
#pragma unroll
                for (int a2 = 0; a2 < 4; ++a2) {
                    a0 = fdot2(em2[2 * a2],     wrk[2 * a2],     a0);
                    a1 = fdot2(em2[2 * a2 + 1], wrk[2 * a2 + 1], a1);
                    c0 = fdot2(em2[2 * a2],     wrv[2 * a2],     c0);
                    c1 = fdot2(em2[2 * a2 + 1], wrv[2 * a2 + 1], c1);
                }
                const float zk = a0 + a1, zv = c0 + c1;
                hk[ii] = (_Float16)(zk * __builtin_amdgcn_rcpf(1.f + __expf(-zk)));
                hv[ii] = (_Float16)(zv * __builtin_amdgcn_rcpf(1.f + __expf(-zv)));
            }
            *(f16x4*)&sh_R[n][q * 16 + 4 * k4] = hk;
            *(f16x4*)&sh_hv[n][q * 16 + 4 * k4] = hv;
        }
    }
    WBAR();
    const int pe = sh_pe[n];

    // ================= K GEMM (B from sh_R h-staging; reads precede dump) ======
    {
        f16x8 B0 = *(const f16x8*)&sh_R[n][q * 8];
        f16x8 B1 = *(const f16x8*)&sh_R[n][32 + q * 8];
        f32x4 acc[18];
#pragma unroll
        for (int t = 0; t < 18; ++t) acc[t] = f32x4{0.f, 0.f, 0.f, 0.f};
#pragma unroll
        for (int t = 0; t < 18; ++t) {
            f16x8 A0 = w2fk[(t * 2 + 0) * 64 + l];
            f16x8 A1 = w2fk[(t * 2 + 1) * 64 + l];
            acc[t] = __builtin_amdgcn_mfma_f32_16x16x32_f16(A0, B0, acc[t], 0, 0, 0);
            acc[t] = __builtin_amdgcn_mfma_f32_16x16x32_f16(A1, B1, acc[t], 0, 0, 0);
        }
#pragma unroll
        for (int t = 0; t < 18; ++t) {
            f16x4 rv = {(_Float16)acc[t][0], (_Float16)acc[t][1],
                        (_Float16)acc[t][2], (_Float16)acc[t][3]};
            *(f16x4*)&sh_R[n][t * 16 + 4 * q] = rv;
        }
    }
    WBAR();
    // ---- k epilogue: score partials (b-sliced; Wd pre-folded into g) ----
    {
        float xr[40];
        const float4* xp = (const float4*)(x + (size_t)i * 40);
#pragma unroll
        for (int p = 0; p < 10; ++p) {
            float4 v = xp[p];
            xr[4 * p] = v.x; xr[4 * p + 1] = v.y;
            xr[4 * p + 2] = v.z; xr[4 * p + 3] = v.w;
        }
        const float* gj = gn + (size_t)j * 20;
        float pd = 0.f;
        if (q < 2) {
            float ssv[4] = {0.f, 0.f, 0.f, 0.f};
            float uuv[4] = {0.f, 0.f, 0.f, 0.f};
#pragma unroll
            for (int a = 0; a < 16; ++a) {
                const f16x4 rv = *(const f16x4*)&sh_R[n][a * 8 + b0];
#pragma unroll
                for (int r = 0; r < 4; ++r) ssv[r] += xr[a] * (float)rv[r];
            }
#pragma unroll
            for (int a = 0; a < 8; ++a) {
                const float xy = xr[16 + a * 3] * y1x + xr[17 + a * 3] * y1y
                               + xr[18 + a * 3] * y1z;
                const f16x4 rv = *(const f16x4*)&sh_R[n][128 + a * 8 + b0];
#pragma unroll
                for (int r = 0; r < 4; ++r) uuv[r] += xy * (float)rv[r];
            }
#pragma unroll
            for (int r = 0; r < 4; ++r)
                pd += (y0 * ssv[r] + uuv[r]) * gj[b0 + r];
        } else {
            float suv[2] = {0.f, 0.f};
            float usv[2][3] = {{0.f, 0.f, 0.f}, {0.f, 0.f, 0.f}};
#pragma unroll
            for (int a = 0; a < 16; ++a) {
                const half2v rv = *(const half2v*)&sh_R[n][192 + a * 4 + b0];
                suv[0] += xr[a] * (float)rv[0];
                suv[1] += xr[a] * (float)rv[1];
            }
#pragma unroll
            for (int a = 0; a < 8; ++a) {
                const half2v rv = *(const half2v*)&sh_R[n][256 + a * 4 + b0];
#pragma unroll
                for (int bb = 0; bb < 2; ++bb) {
                    const float wv = (float)rv[bb];
                    usv[bb][0] += xr[16 + a * 3] * wv;
                    usv[bb][1] += xr[17 + a * 3] * wv;
                    usv[bb][2] += xr[18 + a * 3] * wv;
                }
            }
#pragma unroll
            for (int bb = 0; bb < 2; ++bb) {
                const float k1x = suv[bb] * y1x + y0 * usv[bb][0];
                const float k1y = suv[bb] * y1y + y0 * usv[bb][1];
                const float k1z = suv[bb] * y1z + y0 * usv[bb][2];
                const float* gr = gj + 8 + (b0 + bb) * 3;
                pd += k1x * gr[0] + k1y * gr[1] + k1z * gr[2];
            }
        }
        sh_d[n][q] = pd;
    }
    WBAR();
    if (q == 0) {
        const float d = sh_d[n][0] + sh_d[n][1] + sh_d[n][2] + sh_d[n][3];
        const float len = el[e];
        const float tt = 10.f * (1.f - len / 3.15f);
        float cut = 0.f;
        if (tt > 0.f) cut = __expf(-1.f / fmaxf(tt, 1e-6f));
        evs[pe] = cut * __expf(d);
    }
    WBAR();   // all k-epilogue sh_R reads precede v dump (in-order DS, pinned order)

    // ================= V GEMM (B from sh_hv) =================
    {
        f16x8 B0 = *(const f16x8*)&sh_hv[n][q * 8];
        f16x8 B1 = *(const f16x8*)&sh_hv[n][32 + q * 8];
        f32x4 acc[18];
#pragma unroll
        for (int t = 0; t < 18; ++t) acc[t] = f32x4{0.f, 0.f, 0.f, 0.f};
#pragma unroll
        for (int t = 0; t < 18; ++t) {
            f16x8 A0 = w2fv[(t * 2 + 0) * 64 + l];
            f16x8 A1 = w2fv[(t * 2 + 1) * 64 + l];
            acc[t] = __builtin_amdgcn_mfma_f32_16x16x32_f16(A0, B0, acc[t], 0, 0, 0);
            acc[t] = __builtin_amdgcn_mfma_f32_16x16x32_f16(A1, B1, acc[t], 0, 0, 0);
        }
#pragma unroll
        for (int t = 0; t < 18; ++t) {
            f16x4 rv = {(_Float16)acc[t][0], (_Float16)acc[t][1],
                        (_Float16)acc[t][2], (_Float16)acc[t][3]};
            *(f16x4*)&sh_R[n][t * 16 + 4 * q] = rv;
        }
    }
    WBAR();
    // ---- v epilogue: store 20-half record at CSR slot ----
    {
        float xr[40];
        const float4* xp = (const float4*)(x + (size_t)i * 40);
#pragma unroll
        for (int p = 0; p < 10; ++p) {
            float4 v = xp[p];
            xr[4 * p] = v.x; xr[4 * p + 1] = v.y;
            xr[4 * p + 2] = v.z; xr[4 * p + 3] = v.w;
        }
        _Float16* rec = vsc + (size_t)pe * 20;
        if (q < 2) {
            float ssv[4] = {0.f, 0.f, 0.f, 0.f};
            float uuv[4] = {0.f, 0.f, 0.f, 0.f};
#pragma unroll
            for (int a = 0; a < 16; ++a) {
                const f16x4 rv = *(const f16x4*)&sh_R[n][a * 8 + b0];
#pragma unroll
                for (int r = 0; r < 4; ++r) ssv[r] += xr[a] * (float)rv[r];
            }
#pragma unroll
            for (int a = 0; a < 8; ++a) {
                const float xy = xr[16 + a * 3] * y1x + xr[17 + a * 3] * y1y
                               + xr[18 + a * 3] * y1z;
                const f16x4 rv = *(const f16x4*)&sh_R[n][128 + a * 8 + b0];
#pragma unroll
                for (int r = 0; r < 4; ++r) uuv[r] += xy * (float)rv[r];
            }
            f16x4 o;
#pragma unroll
            for (int r = 0; r < 4; ++r) o[r] = (_Float16)(y0 * ssv[r] + uuv[r]);
            *(f16x4*)&rec[b0] = o;
        } else {
            float suv[2] = {0.f, 0.f};
            float usv[2][3] = {{0.f, 0.f, 0.f}, {0.f, 0.f, 0.f}};
#pragma unroll
            for (int a = 0; a < 16; ++a) {
                const half2v rv = *(const half2v*)&sh_R[n][192 + a * 4 + b0];
                suv[0] += xr[a] * (float)rv[0];
                suv[1] += xr[a] * (float)rv[1];
            }
#pragma unroll
            for (int a = 0; a < 8; ++a) {
                const half2v rv = *(const half2v*)&sh_R[n][256 + a * 4 + b0];
#pragma unroll
                for (int bb = 0; bb < 2; ++bb) {
                    const float wv = (float)rv[bb];
                    usv[bb][0] += xr[16 + a * 3] * wv;
                    usv[bb][1] += xr[17 + a * 3] * wv;
                    usv[bb][2] += xr[18 + a * 3] * wv;
                }
            }
            float k1v[2][3];
#pragma unroll
            for (int bb = 0; bb < 2; ++bb) {
                k1v[bb][0] = suv[bb] * y1x + y0 * usv[bb][0];
                k1v[bb][1] = suv[bb] * y1y + y0 * usv[bb][1];
                k1v[bb][2] = suv[bb] * y1z + y0 * usv[bb][2];
            }
            const int base = 8 + b0 * 3;
            *(half2v*)&rec[base]     = half2v{(_Float16)k1v[0][0], (_Float16)k1v[0][1]};
            *(half2v*)&rec[base + 2] = half2v{(_Float16)k1v[0][2], (_Float16)k1v[1][0]};
            *(half2v*)&rec[base + 4] = half2v{(_Float16)k1v[1][1], (_Float16)k1v[1][2]};
        }
    }
}

// ---------- node gather: one wave per node, all lanes active, zero atomics ----------
__global__ __launch_bounds__(TPB) void node_gather(
    const int* __restrict__ offs,
    const float* __restrict__ evs, const _Float16* __restrict__ vsc,
    float* __restrict__ out)
{
    const int wv = threadIdx.x >> 6, lane = threadIdx.x & 63;
    const int j = blockIdx.x * 4 + wv;
    if (j >= NN) return;
    const int o0 = offs[j], cnt = offs[j + 1] - o0;

    float s = 0.f;
    for (int t = lane; t < cnt; t += 64) s += evs[o0 + t];
#pragma unroll
    for (int d = 1; d < 64; d <<= 1) s += __shfl_xor(s, d);
    const float invZ = (s > 0.f) ? (1.f / s) : 0.f;

    const int g = lane / 20, c = lane % 20;
    float acc = 0.f;
    if (g < 3) {
        for (int t = g; t < cnt; t += 3) {
            const float ev = evs[o0 + t];
            const float wgt = sqrtf(fmaxf(ev * invZ, 0.f));
            acc += wgt * (float)vsc[(size_t)(o0 + t) * 20 + c];
        }
    }
    const float a1 = __shfl(acc, lane + 20);
    const float a2 = __shfl(acc, lane + 40);
    if (lane < 20) out[(size_t)j * 20 + lane] = acc + a1 + a2;
}

extern "C" void kernel_launch(void* const* d_in, const int* in_sizes, int n_in,
                              void* d_out, int out_size, void* d_ws, size_t ws_size,
                              hipStream_t stream)
{
    const float* x     = (const float*)d_in[0];
    const int*   eidx  = (const int*)d_in[1];
    const float* eattr = (const float*)d_in[2];
    const float* emb   = (const float*)d_in[3];
    const float* elen  = (const float*)d_in[4];
    const float* wq0   = (const float*)d_in[5];
    const float* wq1   = (const float*)d_in[6];
    const float* wk1   = (const float*)d_in[7];
    const float* wk2   = (const float*)d_in[8];
    const float* wv1   = (const float*)d_in[9];
    const float* wv2   = (const float*)d_in[10];
    const float* wd0   = (const float*)d_in[11];
    const float* wd1   = (const float*)d_in[12];

    float* ws  = (float*)d_ws;
    float* out = (float*)d_out;

    half2v* w1pk = (half2v*)(ws + NW1K_OFF);
    half2v* w1pv = (half2v*)(ws + NW1V_OFF);
    _Float16* w2fk = (_Float16*)(ws + NW2K_OFF);
    _Float16* w2fv = (_Float16*)(ws + NW2V_OFF);
    int* cnt  = (int*)(ws + NCNT_OFF);
    int* c2   = (int*)(ws + NC2_OFF);
    int* offs = (int*)(ws + NOFF_OFF);
    float* evs = ws + NEVS_OFF;
    _Float16* vsc = (_Float16*)(ws + NVSC_OFF);

    // zero cnt + c2 (adjacent) in one memset
    hipMemsetAsync(cnt, 0, 2 * NN * sizeof(int), stream);

    // prep: weights + g + histogram (1875 hist blocks)
    prep_all<<<136 + NE / TPB, TPB, 0, stream>>>(
        x, eidx, wq0, wq1, wk1, wk2, wv1, wv2, wd0, wd1,
        w1pk, w1pv, w2fk, w2fv, ws + NG_OFF, cnt);

    scan_k<<<1, 1024, 0, stream>>>(cnt, offs);

    edge_fused<<<NE / 16, ETPB, 0, stream>>>(
        x, eidx, eattr, emb, elen,
        w1pk, (const f16x8*)w2fk, w1pv, (const f16x8*)w2fv,
        ws + NG_OFF, offs, c2, evs, vsc);

    node_gather<<<(NN + 3) / 4, TPB, 0, stream>>>(offs, evs, vsc, out);
}

// Round 17
// 340.354 us; speedup vs baseline: 1.9146x; 1.0438x over previous
//
#include <hip/hip_runtime.h>
#include <math.h>

#define NN 30000
#define NE 480000
#define TPB 256
#define ETPB 64

// ---- CSR-path workspace layout (float offsets) ----
// cnt, c2, Z, base are contiguous: zeroed by ONE memset
#define NG_OFF    0           // 600000 g vectors (Wd folded)
#define NW1K_OFF  600000      // 512
#define NW1V_OFF  600512      // 512
#define NW2K_OFF  601024      // 9216
#define NW2V_OFF  610240      // 9216
#define NCNT_OFF  619456      // 30000 int
#define NC2_OFF   649456      // 30000 int
#define NZ_OFF    679456      // 30000 f32
#define NBASE_OFF 709456      // 8 int
#define NOFF_OFF  709464      // 30000 int
#define NEVS_OFF  739464      // 480000 f32
#define NVSC_OFF  1219464     // 9600000 halfs
#define NTOT      6019464     // floats (~24.1 MB)

#define INV_SQRT8  0.35355339059327376f
#define SIG_SS     0.02209708691207961f
#define SIG_UU     0.01804219591217582f
#define SIG_SU     0.02209708691207961f
#define SIG_US     0.03125f
#define D0S        0.08838834764831845f
#define D1S        0.10206207261596575f

// single-wave block: HW executes a wave's DS ops in order; this only pins
// compile-time ordering (no s_barrier, no waitcnt drain). r13-verified.
#define WBAR() __builtin_amdgcn_wave_barrier()

typedef _Float16 half2v __attribute__((ext_vector_type(2)));
typedef _Float16 f16x4  __attribute__((ext_vector_type(4)));
typedef _Float16 f16x8  __attribute__((ext_vector_type(8)));
typedef float    f32x4  __attribute__((ext_vector_type(4)));

__device__ __forceinline__ float fdot2(half2v a, half2v b, float c) {
    return __builtin_amdgcn_fdot2(a, b, c, false);
}

// ---------- fused prep: weight pack (0..17) + g vectors (18..135) + edge hist (136..)
__global__ __launch_bounds__(TPB) void prep_all(
    const float* __restrict__ x, const int* __restrict__ ei,
    const float* __restrict__ wq0, const float* __restrict__ wq1,
    const float* __restrict__ wk1, const float* __restrict__ wk2,
    const float* __restrict__ wv1, const float* __restrict__ wv2,
    const float* __restrict__ wd0, const float* __restrict__ wd1,
    half2v* __restrict__ w1pk, half2v* __restrict__ w1pv,
    _Float16* __restrict__ w2fk, _Float16* __restrict__ w2fv,
    float* __restrict__ g, int* __restrict__ cnt)
{
    const int b = blockIdx.x;
    if (b < 18) {
        int tid = b * TPB + threadIdx.x;   // 4608 exactly
        {
            int p = tid / 2304, rem = tid % 2304;
            int fg = rem >> 6, l = rem & 63;
            int t = fg >> 1, s = fg & 1;
            int kbase = s * 32 + (l >> 4) * 8;
            int m = t * 16 + (l & 15);
            float sig = (m < 128) ? SIG_SS : (m < 192) ? SIG_UU
                      : (m < 256) ? SIG_SU : SIG_US;
            const float* W2 = p ? wv2 : wk2;
            _Float16* dst = (p ? w2fv : w2fk) + (size_t)(fg * 64 + l) * 8;
#pragma unroll
            for (int jj = 0; jj < 8; ++jj)
                dst[jj] = (_Float16)(W2[(size_t)(kbase + jj) * 288 + m] * sig);
        }
        if (tid < 512) {
            int hh = tid >> 3, a2 = tid & 7;
            w1pk[tid] = half2v{(_Float16)(wk1[(2 * a2) * 64 + hh] * 0.25f),
                               (_Float16)(wk1[(2 * a2 + 1) * 64 + hh] * 0.25f)};
            w1pv[tid] = half2v{(_Float16)(wv1[(2 * a2) * 64 + hh] * 0.25f),
                               (_Float16)(wv1[(2 * a2 + 1) * 64 + hh] * 0.25f)};
        }
    } else if (b < 136) {
        // ---- per-node g = Wd-folded q (r12-verified) ----
        int n = (b - 18) * TPB + threadIdx.x;
        if (n >= NN) return;
        const float* xr = x + (size_t)n * 40;
        float* o = g + (size_t)n * 20;
        float q0[8];
#pragma unroll
        for (int bb = 0; bb < 8; ++bb) {
            float acc = 0.f;
#pragma unroll
            for (int a = 0; a < 16; ++a) acc += xr[a] * wq0[a * 8 + bb];
            q0[bb] = acc * 0.25f;
        }
#pragma unroll
        for (int bb = 0; bb < 8; ++bb) {
            float acc = 0.f;
#pragma unroll
            for (int a = 0; a < 8; ++a) acc += q0[a] * wd0[a * 8 + bb];
            o[bb] = acc * D0S;
        }
        float q1[4][3];
#pragma unroll
        for (int bb = 0; bb < 4; ++bb)
#pragma unroll
            for (int c = 0; c < 3; ++c) {
                float acc = 0.f;
#pragma unroll
                for (int a = 0; a < 8; ++a) acc += xr[16 + a * 3 + c] * wq1[a * 4 + bb];
                q1[bb][c] = acc * INV_SQRT8;
            }
#pragma unroll
        for (int bb = 0; bb < 4; ++bb)
#pragma unroll
            for (int c = 0; c < 3; ++c) {
                float acc = 0.f;
#pragma unroll
                for (int a = 0; a < 4; ++a) acc += q1[a][c] * wd1[a * 4 + bb];
                o[8 + bb * 3 + c] = acc * D1S;
            }
    } else {
        // ---- edge histogram (cnt pre-zeroed by memset) ----
        int e = (b - 136) * TPB + threadIdx.x;   // 1875 blocks, exact
        atomicAdd(cnt + ei[NE + e], 1);
    }
}

// ---------- parallel order-free scan: block-local prefix + atomic base ----------
// Bases non-monotonic across blocks; CSR only needs disjoint contiguous segments
// (node_gather reads cnt[j] for lengths, never offs[j+1]-offs[j]).
__global__ __launch_bounds__(TPB) void scan_blk(const int* __restrict__ cnt,
                                                int* __restrict__ offs,
                                                int* __restrict__ base)
{
    __shared__ int sdata[TPB];
    __shared__ int bbase;
    const int t = threadIdx.x;
    const int idx = blockIdx.x * TPB + t;
    const int v = (idx < NN) ? cnt[idx] : 0;
    sdata[t] = v;
    __syncthreads();
    for (int off = 1; off < TPB; off <<= 1) {
        int u = (t >= off) ? sdata[t - off] : 0;
        __syncthreads();
        sdata[t] += u;
        __syncthreads();
    }
    if (t == TPB - 1) bbase = atomicAdd(base, sdata[TPB - 1]);
    __syncthreads();
    if (idx < NN) offs[idx] = bbase + sdata[t] - v;   // exclusive within block
}

// ---------- fused k+v edge kernel (r15-verified; + Z accumulation) ----------
__global__ __launch_bounds__(ETPB, 4) void edge_fused(
    const float* __restrict__ x, const int* __restrict__ ei,
    const float* __restrict__ eattr, const float* __restrict__ emb,
    const float* __restrict__ el,
    const half2v* __restrict__ w1pk, const f16x8* __restrict__ w2fk,
    const half2v* __restrict__ w1pv, const f16x8* __restrict__ w2fv,
    const float* __restrict__ gn, const int* __restrict__ offs,
    int* __restrict__ c2, float* __restrict__ Z,
    float* __restrict__ evs, _Float16* __restrict__ vsc)
{
    __shared__ __align__(16) _Float16 sh_R[16][292];  // h_k staged, then R dumps
    __shared__ __align__(16) _Float16 sh_hv[16][72];  // h_v parked for the V GEMM
    __shared__ float sh_d[16][4];
    __shared__ int sh_pe[16];

    const int l = threadIdx.x;            // single wave
    const int q = l >> 4, n = l & 15;
    const int e = blockIdx.x * 16 + n;
    const int i = ei[e];
    const int j = ei[NE + e];
    const float4 ea = *(const float4*)(eattr + (size_t)e * 4);
    const float y0 = ea.x, y1x = ea.y, y1y = ea.z, y1z = ea.w;
    const int b0 = (q < 2) ? (4 * q) : (2 * (q - 2));

    // in-kernel rank (r13-verified): CSR slot, broadcast via LDS
    if (q == 0) sh_pe[n] = offs[j] + atomicAdd(c2 + j, 1);

    // ---- both hidden layers from ONE em2; h_k -> sh_R, h_v -> sh_hv ----
    {
        half2v em2[8];
        const float4* ep = (const float4*)(emb + (size_t)e * 16);
#pragma unroll
        for (int p = 0; p < 4; ++p) {
            float4 v = ep[p];
            em2[2 * p]     = half2v{(_Float16)v.x, (_Float16)v.y};
            em2[2 * p + 1] = half2v{(_Float16)v.z, (_Float16)v.w};
        }
#pragma unroll
        for (int k4 = 0; k4 < 4; ++k4) {
            f16x4 hk, hv;
#pragma unroll
            for (int ii = 0; ii < 4; ++ii) {
                const int k = q * 16 + 4 * k4 + ii;
                const half2v* wrk = w1pk + (size_t)k * 8;
                const half2v* wrv = w1pv + (size_t)k * 8;
                float a0 = 0.f, a1 = 0.f, c0 = 0.f, c1 = 0.f;
#pragma unroll
                for (int a2 = 0; a2 < 4; ++a2) {
                    a0 = fdot2(em2[2 * a2],     wrk[2 * a2],     a0);
                    a1 = fdot2(em2[2 * a2 + 1], wrk[2 * a2 + 1], a1);
                    c0 = fdot2(em2[2 * a2],     wrv[2 * a2],     c0);
                    c1 = fdot2(em2[2 * a2 + 1], wrv[2 * a2 + 1], c1);
                }
                const float zk = a0 + a1, zv = c0 + c1;
                hk[ii] = (_Float16)(zk * __builtin_amdgcn_rcpf(1.f + __expf(-zk)));
                hv[ii] = (_Float16)(zv * __builtin_amdgcn_rcpf(1.f + __expf(-zv)));
            }
            *(f16x4*)&sh_R[n][q * 16 + 4 * k4] = hk;
            *(f16x4*)&sh_hv[n][q * 16 + 4 * k4] = hv;
        }
    }
    WBAR();
    const int pe = sh_pe[n];

    // ================= K GEMM (B from sh_R h-staging; reads precede dump) ======
    {
        f16x8 B0 = *(const f16x8*)&sh_R[n][q * 8];
        f16x8 B1 = *(const f16x8*)&sh_R[n][32 + q * 8];
        f32x4 acc[18];
#pragma unroll
        for (int t = 0; t < 18; ++t) acc[t] = f32x4{0.f, 0.f, 0.f, 0.f};
#pragma unroll
        for (int t = 0; t < 18; ++t) {
            f16x8 A0 = w2fk[(t * 2 + 0) * 64 + l];
            f16x8 A1 = w2fk[(t * 2 + 1) * 64 + l];
            acc[t] = __builtin_amdgcn_mfma_f32_16x16x32_f16(A0, B0, acc[t], 0, 0, 0);
            acc[t] = __builtin_amdgcn_mfma_f32_16x16x32_f16(A1, B1, acc[t], 0, 0, 0);
        }
#pragma unroll
        for (int t = 0; t < 18; ++t) {
            f16x4 rv = {(_Float16)acc[t][0], (_Float16)acc[t][1],
                        (_Float16)acc[t][2], (_Float16)acc[t][3]};
            *(f16x4*)&sh_R[n][t * 16 + 4 * q] = rv;
        }
    }
    WBAR();
    // ---- k epilogue: score partials (b-sliced; Wd pre-folded into g) ----
    {
        float xr[40];
        const float4* xp = (const float4*)(x + (size_t)i * 40);
#pragma unroll
        for (int p = 0; p < 10; ++p) {
            float4 v = xp[p];
            xr[4 * p] = v.x; xr[4 * p + 1] = v.y;
            xr[4 * p + 2] = v.z; xr[4 * p + 3] = v.w;
        }
        const float* gj = gn + (size_t)j * 20;
        float pd = 0.f;
        if (q < 2) {
            float ssv[4] = {0.f, 0.f, 0.f, 0.f};
            float uuv[4] = {0.f, 0.f, 0.f, 0.f};
#pragma unroll
            for (int a = 0; a < 16; ++a) {
                const f16x4 rv = *(const f16x4*)&sh_R[n][a * 8 + b0];
#pragma unroll
                for (int r = 0; r < 4; ++r) ssv[r] += xr[a] * (float)rv[r];
            }
#pragma unroll
            for (int a = 0; a < 8; ++a) {
                const float xy = xr[16 + a * 3] * y1x + xr[17 + a * 3] * y1y
                               + xr[18 + a * 3] * y1z;
                const f16x4 rv = *(const f16x4*)&sh_R[n][128 + a * 8 + b0];
#pragma unroll
                for (int r = 0; r < 4; ++r) uuv[r] += xy * (float)rv[r];
            }
#pragma unroll
            for (int r = 0; r < 4; ++r)
                pd += (y0 * ssv[r] + uuv[r]) * gj[b0 + r];
        } else {
            float suv[2] = {0.f, 0.f};
            float usv[2][3] = {{0.f, 0.f, 0.f}, {0.f, 0.f, 0.f}};
#pragma unroll
            for (int a = 0; a < 16; ++a) {
                const half2v rv = *(const half2v*)&sh_R[n][192 + a * 4 + b0];
                suv[0] += xr[a] * (float)rv[0];
                suv[1] += xr[a] * (float)rv[1];
            }
#pragma unroll
            for (int a = 0; a < 8; ++a) {
                const half2v rv = *(const half2v*)&sh_R[n][256 + a * 4 + b0];
#pragma unroll
                for (int bb = 0; bb < 2; ++bb) {
                    const float wv = (float)rv[bb];
                    usv[bb][0] += xr[16 + a * 3] * wv;
                    usv[bb][1] += xr[17 + a * 3] * wv;
                    usv[bb][2] += xr[18 + a * 3] * wv;
                }
            }
#pragma unroll
            for (int bb = 0; bb < 2; ++bb) {
                const float k1x = suv[bb] * y1x + y0 * usv[bb][0];
                const float k1y = suv[bb] * y1y + y0 * usv[bb][1];
                const float k1z = suv[bb] * y1z + y0 * usv[bb][2];
                const float* gr = gj + 8 + (b0 + bb) * 3;
                pd += k1x * gr[0] + k1y * gr[1] + k1z * gr[2];
            }
        }
        sh_d[n][q] = pd;
    }
    WBAR();
    if (q == 0) {
        const float d = sh_d[n][0] + sh_d[n][1] + sh_d[n][2] + sh_d[n][3];
        const float len = el[e];
        const float tt = 10.f * (1.f - len / 3.15f);
        float cut = 0.f;
        if (tt > 0.f) cut = __expf(-1.f / fmaxf(tt, 1e-6f));
        const float ev = cut * __expf(d);
        evs[pe] = ev;
        atomicAdd(Z + j, ev);
    }
    WBAR();   // all k-epilogue sh_R reads precede v dump (in-order DS, pinned order)

    // ================= V GEMM (B from sh_hv) =================
    {
        f16x8 B0 = *(const f16x8*)&sh_hv[n][q * 8];
        f16x8 B1 = *(const f16x8*)&sh_hv[n][32 + q * 8];
        f32x4 acc[18];
#pragma unroll
        for (int t = 0; t < 18; ++t) acc[t] = f32x4{0.f, 0.f, 0.f, 0.f};
#pragma unroll
        for (int t = 0; t < 18; ++t) {
            f16x8 A0 = w2fv[(t * 2 + 0) * 64 + l];
            f16x8 A1 = w2fv[(t * 2 + 1) * 64 + l];
            acc[t] = __builtin_amdgcn_mfma_f32_16x16x32_f16(A0, B0, acc[t], 0, 0, 0);
            acc[t] = __builtin_amdgcn_mfma_f32_16x16x32_f16(A1, B1, acc[t], 0, 0, 0);
        }
#pragma unroll
        for (int t = 0; t < 18; ++t) {
            f16x4 rv = {(_Float16)acc[t][0], (_Float16)acc[t][1],
                        (_Float16)acc[t][2], (_Float16)acc[t][3]};
            *(f16x4*)&sh_R[n][t * 16 + 4 * q] = rv;
        }
    }
    WBAR();
    // ---- v epilogue: store 20-half record at CSR slot ----
    {
        float xr[40];
        const float4* xp = (const float4*)(x + (size_t)i * 40);
#pragma unroll
        for (int p = 0; p < 10; ++p) {
            float4 v = xp[p];
            xr[4 * p] = v.x; xr[4 * p + 1] = v.y;
            xr[4 * p + 2] = v.z; xr[4 * p + 3] = v.w;
        }
        _Float16* rec = vsc + (size_t)pe * 20;
        if (q < 2) {
            float ssv[4] = {0.f, 0.f, 0.f, 0.f};
            float uuv[4] = {0.f, 0.f, 0.f, 0.f};
#pragma unroll
            for (int a = 0; a < 16; ++a) {
                const f16x4 rv = *(const f16x4*)&sh_R[n][a * 8 + b0];
#pragma unroll
                for (int r = 0; r < 4; ++r) ssv[r] += xr[a] * (float)rv[r];
            }
#pragma unroll
            for (int a = 0; a < 8; ++a) {
                const float xy = xr[16 + a * 3] * y1x + xr[17 + a * 3] * y1y
                               + xr[18 + a * 3] * y1z;
                const f16x4 rv = *(const f16x4*)&sh_R[n][128 + a * 8 + b0];
#pragma unroll
                for (int r = 0; r < 4; ++r) uuv[r] += xy * (float)rv[r];
            }
            f16x4 o;
#pragma unroll
            for (int r = 0; r < 4; ++r) o[r] = (_Float16)(y0 * ssv[r] + uuv[r]);
            *(f16x4*)&rec[b0] = o;
        } else {
            float suv[2] = {0.f, 0.f};
            float usv[2][3] = {{0.f, 0.f, 0.f}, {0.f, 0.f, 0.f}};
#pragma unroll
            for (int a = 0; a < 16; ++a) {
                const half2v rv = *(const half2v*)&sh_R[n][192 + a * 4 + b0];
                suv[0] += xr[a] * (float)rv[0];
                suv[1] += xr[a] * (float)rv[1];
            }
#pragma unroll
            for (int a = 0; a < 8; ++a) {
                const half2v rv = *(const half2v*)&sh_R[n][256 + a * 4 + b0];
#pragma unroll
                for (int bb = 0; bb < 2; ++bb) {
                    const float wv = (float)rv[bb];
                    usv[bb][0] += xr[16 + a * 3] * wv;
                    usv[bb][1] += xr[17 + a * 3] * wv;
                    usv[bb][2] += xr[18 + a * 3] * wv;
                }
            }
            float k1v[2][3];
#pragma unroll
            for (int bb = 0; bb < 2; ++bb) {
                k1v[bb][0] = suv[bb] * y1x + y0 * usv[bb][0];
                k1v[bb][1] = suv[bb] * y1y + y0 * usv[bb][1];
                k1v[bb][2] = suv[bb] * y1z + y0 * usv[bb][2];
            }
            const int base = 8 + b0 * 3;
            *(half2v*)&rec[base]     = half2v{(_Float16)k1v[0][0], (_Float16)k1v[0][1]};
            *(half2v*)&rec[base + 2] = half2v{(_Float16)k1v[0][2], (_Float16)k1v[1][0]};
            *(half2v*)&rec[base + 4] = half2v{(_Float16)k1v[1][1], (_Float16)k1v[1][2]};
        }
    }
}

// ---------- node gather: Z precomputed; single weighted pass, zero atomics ----------
__global__ __launch_bounds__(TPB) void node_gather(
    const int* __restrict__ offs, const int* __restrict__ cntp,
    const float* __restrict__ Z,
    const float* __restrict__ evs, const _Float16* __restrict__ vsc,
    float* __restrict__ out)
{
    const int wv = threadIdx.x >> 6, lane = threadIdx.x & 63;
    const int j = blockIdx.x * 4 + wv;
    if (j >= NN) return;
    const int o0 = offs[j], cnt = cntp[j];
    const float zz = Z[j];
    const float invZ = (zz > 0.f) ? (1.f / zz) : 0.f;

    const int g = lane / 20, c = lane % 20;
    float acc = 0.f;
    if (g < 3) {
        for (int t = g; t < cnt; t += 3) {
            const float ev = evs[o0 + t];
            const float wgt = sqrtf(fmaxf(ev * invZ, 0.f));
            acc += wgt * (float)vsc[(size_t)(o0 + t) * 20 + c];
        }
    }
    const float a1 = __shfl(acc, lane + 20);
    const float a2 = __shfl(acc, lane + 40);
    if (lane < 20) out[(size_t)j * 20 + lane] = acc + a1 + a2;
}

extern "C" void kernel_launch(void* const* d_in, const int* in_sizes, int n_in,
                              void* d_out, int out_size, void* d_ws, size_t ws_size,
                              hipStream_t stream)
{
    const float* x     = (const float*)d_in[0];
    const int*   eidx  = (const int*)d_in[1];
    const float* eattr = (const float*)d_in[2];
    const float* emb   = (const float*)d_in[3];
    const float* elen  = (const float*)d_in[4];
    const float* wq0   = (const float*)d_in[5];
    const float* wq1   = (const float*)d_in[6];
    const float* wk1   = (const float*)d_in[7];
    const float* wk2   = (const float*)d_in[8];
    const float* wv1   = (const float*)d_in[9];
    const float* wv2   = (const float*)d_in[10];
    const float* wd0   = (const float*)d_in[11];
    const float* wd1   = (const float*)d_in[12];

    float* ws  = (float*)d_ws;
    float* out = (float*)d_out;

    half2v* w1pk = (half2v*)(ws + NW1K_OFF);
    half2v* w1pv = (half2v*)(ws + NW1V_OFF);
    _Float16* w2fk = (_Float16*)(ws + NW2K_OFF);
    _Float16* w2fv = (_Float16*)(ws + NW2V_OFF);
    int* cnt  = (int*)(ws + NCNT_OFF);
    int* c2   = (int*)(ws + NC2_OFF);
    float* Z  = ws + NZ_OFF;
    int* base = (int*)(ws + NBASE_OFF);
    int* offs = (int*)(ws + NOFF_OFF);
    float* evs = ws + NEVS_OFF;
    _Float16* vsc = (_Float16*)(ws + NVSC_OFF);

    // zero cnt + c2 + Z + base (contiguous) in one memset
    hipMemsetAsync(cnt, 0, (3 * NN + 8) * sizeof(int), stream);

    // prep: weights + g + histogram (1875 hist blocks)
    prep_all<<<136 + NE / TPB, TPB, 0, stream>>>(
        x, eidx, wq0, wq1, wk1, wk2, wv1, wv2, wd0, wd1,
        w1pk, w1pv, w2fk, w2fv, ws + NG_OFF, cnt);

    scan_blk<<<(NN + TPB - 1) / TPB, TPB, 0, stream>>>(cnt, offs, base);

    edge_fused<<<NE / 16, ETPB, 0, stream>>>(
        x, eidx, eattr, emb, elen,
        w1pk, (const f16x8*)w2fk, w1pv, (const f16x8*)w2fv,
        ws + NG_OFF, offs, c2, Z, evs, vsc);

    node_gather<<<(NN + 3) / 4, TPB, 0, stream>>>(offs, cnt, Z, evs, vsc, out);
}